// Round 3
// baseline (407.047 us; speedup 1.0000x reference)
//
#include <hip/hip_runtime.h>
#include <stdint.h>

// Problem constants: B=2, S=2048, D=1024, H=16, HD=64, ROT_DIM=64(=HD)
#define S_LEN 2048
#define NHEAD 16
#define DMODEL 1024

typedef __attribute__((ext_vector_type(8))) short short8;
typedef __attribute__((ext_vector_type(8))) __bf16 bf16x8;
typedef __attribute__((ext_vector_type(4))) float f32x4;

__device__ __forceinline__ unsigned short f2b(float f) {
  unsigned int u = __float_as_uint(f);
  u += 0x7fffu + ((u >> 16) & 1u);   // round-to-nearest-even
  return (unsigned short)(u >> 16);
}
__device__ __forceinline__ float b2f(unsigned short h) {
  return __uint_as_float(((unsigned int)h) << 16);
}
__device__ __forceinline__ f32x4 mfma16(short8 a, short8 b, f32x4 c) {
  return __builtin_amdgcn_mfma_f32_16x16x32_bf16(
      __builtin_bit_cast(bf16x8, a), __builtin_bit_cast(bf16x8, b), c, 0, 0, 0);
}
__device__ __forceinline__ void gload16(const void* g, void* l) {
  __builtin_amdgcn_global_load_lds(
      (const __attribute__((address_space(1))) unsigned int*)g,
      (__attribute__((address_space(3))) unsigned int*)l, 16, 0, 0);
}

// ---------------- cast x (f32 -> bf16), vectorized ----------------
__global__ __launch_bounds__(256) void cast_f32_bf16(
    const float* __restrict__ in, unsigned short* __restrict__ out, long n) {
  long i = ((long)blockIdx.x * 256 + threadIdx.x) * 4;
  if (i >= n) return;
  float4 v = *(const float4*)(in + i);
  ushort4 o;
  o.x = f2b(v.x); o.y = f2b(v.y); o.z = f2b(v.z); o.w = f2b(v.w);
  *(ushort4*)(out + i) = o;
}

// ---------------- transpose + cast: W[K][N] f32 -> Wt[N][K] bf16 ----------------
__global__ __launch_bounds__(256) void transpose_cast(
    const float* __restrict__ W, unsigned short* __restrict__ Wt, int K, int N) {
  __shared__ float t[32][33];
  const int nt = blockIdx.x, kt = blockIdx.y;
  const int tx = threadIdx.x, ty = threadIdx.y; // (32, 8)
#pragma unroll
  for (int j = 0; j < 4; ++j)
    t[ty + j * 8][tx] = W[(long)(kt * 32 + ty + j * 8) * N + nt * 32 + tx];
  __syncthreads();
#pragma unroll
  for (int j = 0; j < 4; ++j)
    Wt[(long)(nt * 32 + ty + j * 8) * K + kt * 32 + tx] = f2b(t[tx][ty + j * 8]);
}

// ---------------- RoPE cos/sin table: tab[s*32+i] = (cos, sin) of s*inv_freq(i) ----------------
__global__ __launch_bounds__(256) void make_tab(float2* __restrict__ tab) {
  int i = blockIdx.x * 256 + threadIdx.x;  // 2048*32
  if (i >= S_LEN * 32) return;
  int s = i >> 5, fi = i & 31;
  float inv = powf(10000.0f, -(float)(2 * fi) / 64.0f);
  float fr = (float)s * inv;
  tab[i] = make_float2(cosf(fr), sinf(fr));
}

// ---------------- GEMM: C[M][N] = A[M][K](bf16) * Bt[N][K](bf16)^T ----------------
// 128x128 tile, BK=32, 4 waves (2x2), 16x16x32 MFMA, global_load_lds staging.
template <int OUT_BF16>
__global__ __launch_bounds__(256) void gemm_bt(
    const unsigned short* __restrict__ A, const unsigned short* __restrict__ Bt,
    void* __restrict__ Cout, int M, int N, int K) {
  __shared__ __align__(16) unsigned short As[128 * 32];
  __shared__ __align__(16) unsigned short Bs[128 * 32];
  const int tid = threadIdx.x;
  const int wave = tid >> 6, lane = tid & 63;
  const int g = lane >> 4, r15 = lane & 15;
  const int wm = wave >> 1, wn = wave & 1;
  const long m0 = (long)blockIdx.x * 128, n0 = (long)blockIdx.y * 128;
  const int srow = tid >> 2, scol = (tid & 3) * 8;  // 16B per thread
  const unsigned short* Ag = A + (m0 + srow) * K + scol;
  const unsigned short* Bg = Bt + (n0 + srow) * K + scol;
  unsigned short* As0 = &As[srow * 32 + scol];
  unsigned short* As1 = &As[(srow + 64) * 32 + scol];
  unsigned short* Bs0 = &Bs[srow * 32 + scol];
  unsigned short* Bs1 = &Bs[(srow + 64) * 32 + scol];
  f32x4 acc[4][4] = {};
  for (int kt = 0; kt < K; kt += 32) {
    __syncthreads();  // prior reads done before overwrite
    gload16(Ag + kt, As0);
    gload16(Ag + (long)64 * K + kt, As1);
    gload16(Bg + kt, Bs0);
    gload16(Bg + (long)64 * K + kt, Bs1);
    __syncthreads();  // drains vmcnt for global_load_lds
    short8 a[4], b[4];
#pragma unroll
    for (int m = 0; m < 4; ++m)
      a[m] = *(const short8*)&As[(wm * 64 + m * 16 + r15) * 32 + g * 8];
#pragma unroll
    for (int n = 0; n < 4; ++n)
      b[n] = *(const short8*)&Bs[(wn * 64 + n * 16 + r15) * 32 + g * 8];
#pragma unroll
    for (int m = 0; m < 4; ++m)
#pragma unroll
      for (int n = 0; n < 4; ++n)
        acc[m][n] = mfma16(a[m], b[n], acc[m][n]);
  }
#pragma unroll
  for (int m = 0; m < 4; ++m)
#pragma unroll
    for (int n = 0; n < 4; ++n)
#pragma unroll
      for (int r = 0; r < 4; ++r) {
        long row = m0 + wm * 64 + m * 16 + g * 4 + r;
        long col = n0 + wn * 64 + n * 16 + r15;
        if (OUT_BF16)
          ((unsigned short*)Cout)[row * N + col] = f2b(acc[m][n][r]);
        else
          ((float*)Cout)[row * N + col] = acc[m][n][r];
      }
}

// ---------------- RoPE + scatter q,k: qkv[4096][3072] cols 0..2047 -> Qb, Kb [BH][S][64] ----------------
__global__ __launch_bounds__(256) void rope_scatter(
    const unsigned short* __restrict__ qkv, const float2* __restrict__ tab,
    unsigned short* __restrict__ Qb, unsigned short* __restrict__ Kb) {
  long p = (long)blockIdx.x * 256 + threadIdx.x;  // pair index, 4096*1024 total
  if (p >= (long)4096 * 1024) return;
  int row = (int)(p >> 10);
  int col = ((int)(p & 1023)) * 2;
  int seg = col >> 10;            // 0=q, 1=k
  int cc = col & 1023;
  int h = cc >> 6, d = cc & 63;
  int b = row >> 11, s = row & 2047;
  const unsigned short* src = qkv + (long)row * 3072 + col;
  float v0 = b2f(src[0]), v1 = b2f(src[1]);
  float2 f = tab[s * 32 + (d >> 1)];
  float o0 = v0 * f.x + v1 * f.y;   // reference: x*cos - rotate(x)*sin
  float o1 = v1 * f.x - v0 * f.y;
  float scl = seg ? 1.0f : 0.125f;  // q pre-scaled by 1/sqrt(HD)
  unsigned short* dst = (seg ? Kb : Qb) + (((long)(b * NHEAD + h) * S_LEN + s) * 64 + d);
  dst[0] = f2b(o0 * scl);
  dst[1] = f2b(o1 * scl);
}

// ---------------- V transpose: qkv cols 2048.. -> Vt [BH][64][S] ----------------
__global__ __launch_bounds__(256) void v_transpose(
    const unsigned short* __restrict__ qkv, unsigned short* __restrict__ Vt) {
  __shared__ unsigned short t[32][33];
  const int st = blockIdx.x;   // 64 s-tiles
  const int dt = blockIdx.y;   // 2 d-tiles
  const int bh = blockIdx.z;   // 32
  const int b = bh >> 4, h = bh & 15;
  const int tx = threadIdx.x, ty = threadIdx.y;  // (32, 8)
#pragma unroll
  for (int j = 0; j < 4; ++j)
    t[ty + j * 8][tx] =
        qkv[((long)b * S_LEN + st * 32 + ty + j * 8) * 3072 + 2048 + h * 64 + dt * 32 + tx];
  __syncthreads();
#pragma unroll
  for (int j = 0; j < 4; ++j)
    Vt[((long)bh * 64 + dt * 32 + ty + j * 8) * S_LEN + st * 32 + tx] = t[tx][ty + j * 8];
}

// ---------------- flash attention ----------------
// grid (32 qt, 32 bh), 256 thr = 4 waves; wave owns 16 q-rows; KV tile = 32.
__global__ __launch_bounds__(256) void attn_kernel(
    const unsigned short* __restrict__ Qb, const unsigned short* __restrict__ Kb,
    const unsigned short* __restrict__ Vt, unsigned short* __restrict__ yb) {
  const int bh = blockIdx.y;
  const int qt = (int)gridDim.x - 1 - (int)blockIdx.x;  // big-work blocks first
  const int wave = threadIdx.x >> 6, lane = threadIdx.x & 63;
  const int g = lane >> 4, c = lane & 15;
  const int qbase = qt * 64 + wave * 16;
  const unsigned short* Qp = Qb + ((long)bh * S_LEN + qbase) * 64;
  const unsigned short* Kp = Kb + (long)bh * S_LEN * 64;
  const unsigned short* Vp = Vt + (long)bh * 64 * S_LEN;
  __shared__ __align__(16) unsigned short P_lds[4][16 * 32];
  unsigned short* Pw = P_lds[wave];

  const short8 q0 = *(const short8*)(Qp + c * 64 + g * 8);        // A[q=c][d=g*8+j]
  const short8 q1 = *(const short8*)(Qp + c * 64 + 32 + g * 8);
  f32x4 O[4] = {};
  float mrow[4] = {-1e30f, -1e30f, -1e30f, -1e30f};
  float lrow[4] = {0.f, 0.f, 0.f, 0.f};
  const int ntile = (qbase + 16 + 31) >> 5;
  for (int kt = 0; kt < ntile; ++kt) {
    const int kpos0 = kt * 32;
    const unsigned short* K0 = Kp + (long)(kpos0 + c) * 64;
    short8 k00 = *(const short8*)(K0 + g * 8);            // B[d][kpos=kpos0+c]
    short8 k01 = *(const short8*)(K0 + 32 + g * 8);
    short8 k10 = *(const short8*)(K0 + 16 * 64 + g * 8);
    short8 k11 = *(const short8*)(K0 + 16 * 64 + 32 + g * 8);
    f32x4 s0 = {}, s1 = {};
    s0 = mfma16(q0, k00, s0);
    s0 = mfma16(q1, k01, s0);
    s1 = mfma16(q0, k10, s1);
    s1 = mfma16(q1, k11, s1);
    // online softmax: s{0,1}[r] is (q = qbase+g*4+r, kpos = kpos0+{c, 16+c})
    float sc[4], p0[4], p1[4];
#pragma unroll
    for (int r = 0; r < 4; ++r) {
      const int q = qbase + g * 4 + r;
      float a0 = (kpos0 + c <= q) ? s0[r] : -1e30f;
      float a1 = (kpos0 + 16 + c <= q) ? s1[r] : -1e30f;
      float mt = fmaxf(a0, a1);
      mt = fmaxf(mt, __shfl_xor(mt, 1));
      mt = fmaxf(mt, __shfl_xor(mt, 2));
      mt = fmaxf(mt, __shfl_xor(mt, 4));
      mt = fmaxf(mt, __shfl_xor(mt, 8));
      const float mnew = fmaxf(mrow[r], mt);
      const float scale = __expf(mrow[r] - mnew);
      a0 = __expf(a0 - mnew);
      a1 = __expf(a1 - mnew);
      float rs = a0 + a1;
      rs += __shfl_xor(rs, 1);
      rs += __shfl_xor(rs, 2);
      rs += __shfl_xor(rs, 4);
      rs += __shfl_xor(rs, 8);
      lrow[r] = lrow[r] * scale + rs;
      mrow[r] = mnew;
      sc[r] = scale;
      p0[r] = a0;
      p1[r] = a1;
    }
#pragma unroll
    for (int dt = 0; dt < 4; ++dt) {
      f32x4 o = O[dt];
      o[0] *= sc[0]; o[1] *= sc[1]; o[2] *= sc[2]; o[3] *= sc[3];
      O[dt] = o;
    }
    // P (C-layout) -> LDS [q][kpos], wave-private (wave-synchronous, no barrier)
#pragma unroll
    for (int r = 0; r < 4; ++r) {
      Pw[(g * 4 + r) * 32 + c] = f2b(p0[r]);
      Pw[(g * 4 + r) * 32 + 16 + c] = f2b(p1[r]);
    }
    __builtin_amdgcn_wave_barrier();
    const short8 pa = *(const short8*)&Pw[c * 32 + g * 8];  // A[q=c][kpos=g*8+j]
#pragma unroll
    for (int dt = 0; dt < 4; ++dt) {
      const short8 vf = *(const short8*)(Vp + (long)(dt * 16 + c) * S_LEN + kpos0 + g * 8);
      O[dt] = mfma16(pa, vf, O[dt]);
    }
    __builtin_amdgcn_wave_barrier();
  }
  float inv[4];
#pragma unroll
  for (int r = 0; r < 4; ++r) inv[r] = 1.0f / lrow[r];
  const int b = bh >> 4, h = bh & 15;
#pragma unroll
  for (int dt = 0; dt < 4; ++dt)
#pragma unroll
    for (int r = 0; r < 4; ++r) {
      long row = (long)b * S_LEN + qbase + g * 4 + r;
      int col = h * 64 + dt * 16 + c;
      yb[row * DMODEL + col] = f2b(O[dt][r] * inv[r]);
    }
}

extern "C" void kernel_launch(void* const* d_in, const int* in_sizes, int n_in,
                              void* d_out, int out_size, void* d_ws, size_t ws_size,
                              hipStream_t stream) {
  const float* x = (const float*)d_in[0];       // [2,2048,1024]
  const float* Wa = (const float*)d_in[1];      // [1024,3072]
  const float* Wp = (const float*)d_in[2];      // [1024,1024]
  // d_in[3]/d_in[4]: cache_k/cache_v — fully overwritten by k,v (S==cache len), unused.
  float* out = (float*)d_out;

  char* ws = (char*)d_ws;
  size_t off = 0;
  auto alloc = [&](size_t bytes) -> void* {
    off = (off + 255) & ~(size_t)255;
    void* p = ws + off;
    off += bytes;
    return p;
  };
  unsigned short* xb   = (unsigned short*)alloc((size_t)4096 * 1024 * 2);
  unsigned short* WaT  = (unsigned short*)alloc((size_t)3072 * 1024 * 2);
  unsigned short* WpT  = (unsigned short*)alloc((size_t)1024 * 1024 * 2);
  unsigned short* qkvb = (unsigned short*)alloc((size_t)4096 * 3072 * 2);
  float2* tab          = (float2*)alloc((size_t)2048 * 32 * sizeof(float2));
  unsigned short* Qb   = (unsigned short*)alloc((size_t)32 * 2048 * 64 * 2);
  unsigned short* Kb   = (unsigned short*)alloc((size_t)32 * 2048 * 64 * 2);
  unsigned short* Vt   = (unsigned short*)alloc((size_t)32 * 2048 * 64 * 2);
  unsigned short* yb   = xb;  // alias: xb dead after gemm1; attn runs after gemm1 on stream

  dim3 tB(32, 8);
  cast_f32_bf16<<<4096, 256, 0, stream>>>(x, xb, (long)4096 * 1024);
  transpose_cast<<<dim3(96, 32), tB, 0, stream>>>(Wa, WaT, 1024, 3072);
  transpose_cast<<<dim3(32, 32), tB, 0, stream>>>(Wp, WpT, 1024, 1024);
  make_tab<<<256, 256, 0, stream>>>(tab);
  gemm_bt<1><<<dim3(32, 24), 256, 0, stream>>>(xb, WaT, (void*)qkvb, 4096, 3072, 1024);
  rope_scatter<<<16384, 256, 0, stream>>>(qkvb, tab, Qb, Kb);
  v_transpose<<<dim3(64, 2, 32), tB, 0, stream>>>(qkvb, Vt);
  attn_kernel<<<dim3(32, 32), 256, 0, stream>>>(Qb, Kb, Vt, yb);
  gemm_bt<0><<<dim3(32, 8), 256, 0, stream>>>(yb, WpT, (void*)out, 4096, 1024, 1024);
}

// Round 6
// 297.678 us; speedup vs baseline: 1.3674x; 1.3674x over previous
//
#include <hip/hip_runtime.h>
#include <stdint.h>

// Problem constants: B=2, S=2048, D=1024, H=16, HD=64, ROT_DIM=64(=HD)
#define S_LEN 2048
#define NHEAD 16
#define DMODEL 1024

typedef __attribute__((ext_vector_type(8))) short short8;
typedef __attribute__((ext_vector_type(8))) __bf16 bf16x8;
typedef __attribute__((ext_vector_type(4))) float f32x4;

__device__ __forceinline__ unsigned short f2b(float f) {
  unsigned int u = __float_as_uint(f);
  u += 0x7fffu + ((u >> 16) & 1u);   // round-to-nearest-even
  return (unsigned short)(u >> 16);
}
__device__ __forceinline__ float b2f(unsigned short h) {
  return __uint_as_float(((unsigned int)h) << 16);
}
__device__ __forceinline__ f32x4 mfma16(short8 a, short8 b, f32x4 c) {
  return __builtin_amdgcn_mfma_f32_16x16x32_bf16(
      __builtin_bit_cast(bf16x8, a), __builtin_bit_cast(bf16x8, b), c, 0, 0, 0);
}
__device__ __forceinline__ void gload16(const void* g, void* l) {
  __builtin_amdgcn_global_load_lds(
      (const __attribute__((address_space(1))) unsigned int*)g,
      (__attribute__((address_space(3))) unsigned int*)l, 16, 0, 0);
}

// ---------------- cast x (f32 -> bf16), vectorized ----------------
__global__ __launch_bounds__(256) void cast_f32_bf16(
    const float* __restrict__ in, unsigned short* __restrict__ out, long n) {
  long i = ((long)blockIdx.x * 256 + threadIdx.x) * 4;
  if (i >= n) return;
  float4 v = *(const float4*)(in + i);
  ushort4 o;
  o.x = f2b(v.x); o.y = f2b(v.y); o.z = f2b(v.z); o.w = f2b(v.w);
  *(ushort4*)(out + i) = o;
}

// ---------------- transpose + cast: W[K][N] f32 -> Wt[N][K] bf16 ----------------
__global__ __launch_bounds__(256) void transpose_cast(
    const float* __restrict__ W, unsigned short* __restrict__ Wt, int K, int N) {
  __shared__ float t[32][33];
  const int nt = blockIdx.x, kt = blockIdx.y;
  const int tx = threadIdx.x, ty = threadIdx.y; // (32, 8)
#pragma unroll
  for (int j = 0; j < 4; ++j)
    t[ty + j * 8][tx] = W[(long)(kt * 32 + ty + j * 8) * N + nt * 32 + tx];
  __syncthreads();
#pragma unroll
  for (int j = 0; j < 4; ++j)
    Wt[(long)(nt * 32 + ty + j * 8) * K + kt * 32 + tx] = f2b(t[tx][ty + j * 8]);
}

// ---------------- RoPE cos/sin table ----------------
__global__ __launch_bounds__(256) void make_tab(float2* __restrict__ tab) {
  int i = blockIdx.x * 256 + threadIdx.x;  // 2048*32
  if (i >= S_LEN * 32) return;
  int s = i >> 5, fi = i & 31;
  float inv = powf(10000.0f, -(float)(2 * fi) / 64.0f);
  float fr = (float)s * inv;
  tab[i] = make_float2(cosf(fr), sinf(fr));
}

// ---------------- GEMM: C[M][N] = A[M][K](bf16) * Bt[N][K](bf16)^T ----------------
template <int OUT_BF16>
__global__ __launch_bounds__(256) void gemm_bt(
    const unsigned short* __restrict__ A, const unsigned short* __restrict__ Bt,
    void* __restrict__ Cout, int M, int N, int K) {
  __shared__ __align__(16) unsigned short As[128 * 32];
  __shared__ __align__(16) unsigned short Bs[128 * 32];
  const int tid = threadIdx.x;
  const int wave = tid >> 6, lane = tid & 63;
  const int g = lane >> 4, r15 = lane & 15;
  const int wm = wave >> 1, wn = wave & 1;
  const long m0 = (long)blockIdx.x * 128, n0 = (long)blockIdx.y * 128;
  const int srow = tid >> 2, scol = (tid & 3) * 8;  // 16B per thread
  const unsigned short* Ag = A + (m0 + srow) * K + scol;
  const unsigned short* Bg = Bt + (n0 + srow) * K + scol;
  unsigned short* As0 = &As[srow * 32 + scol];
  unsigned short* As1 = &As[(srow + 64) * 32 + scol];
  unsigned short* Bs0 = &Bs[srow * 32 + scol];
  unsigned short* Bs1 = &Bs[(srow + 64) * 32 + scol];
  f32x4 acc[4][4] = {};
  for (int kt = 0; kt < K; kt += 32) {
    __syncthreads();
    gload16(Ag + kt, As0);
    gload16(Ag + (long)64 * K + kt, As1);
    gload16(Bg + kt, Bs0);
    gload16(Bg + (long)64 * K + kt, Bs1);
    __syncthreads();
    short8 a[4], b[4];
#pragma unroll
    for (int m = 0; m < 4; ++m)
      a[m] = *(const short8*)&As[(wm * 64 + m * 16 + r15) * 32 + g * 8];
#pragma unroll
    for (int n = 0; n < 4; ++n)
      b[n] = *(const short8*)&Bs[(wn * 64 + n * 16 + r15) * 32 + g * 8];
#pragma unroll
    for (int m = 0; m < 4; ++m)
#pragma unroll
      for (int n = 0; n < 4; ++n)
        acc[m][n] = mfma16(a[m], b[n], acc[m][n]);
  }
#pragma unroll
  for (int m = 0; m < 4; ++m)
#pragma unroll
    for (int n = 0; n < 4; ++n)
#pragma unroll
      for (int r = 0; r < 4; ++r) {
        long row = m0 + wm * 64 + m * 16 + g * 4 + r;
        long col = n0 + wn * 64 + n * 16 + r15;
        if (OUT_BF16)
          ((unsigned short*)Cout)[row * N + col] = f2b(acc[m][n][r]);
        else
          ((float*)Cout)[row * N + col] = acc[m][n][r];
      }
}

// ---------------- RoPE + scatter q,k ----------------
__global__ __launch_bounds__(256) void rope_scatter(
    const unsigned short* __restrict__ qkv, const float2* __restrict__ tab,
    unsigned short* __restrict__ Qb, unsigned short* __restrict__ Kb) {
  long p = (long)blockIdx.x * 256 + threadIdx.x;  // pair index, 4096*1024 total
  if (p >= (long)4096 * 1024) return;
  int row = (int)(p >> 10);
  int col = ((int)(p & 1023)) * 2;
  int seg = col >> 10;            // 0=q, 1=k
  int cc = col & 1023;
  int h = cc >> 6, d = cc & 63;
  int b = row >> 11, s = row & 2047;
  const unsigned short* src = qkv + (long)row * 3072 + col;
  float v0 = b2f(src[0]), v1 = b2f(src[1]);
  float2 f = tab[s * 32 + (d >> 1)];
  float o0 = v0 * f.x + v1 * f.y;
  float o1 = v1 * f.x - v0 * f.y;
  float scl = seg ? 1.0f : 0.125f;  // q pre-scaled by 1/sqrt(HD)
  unsigned short* dst = (seg ? Kb : Qb) + (((long)(b * NHEAD + h) * S_LEN + s) * 64 + d);
  dst[0] = f2b(o0 * scl);
  dst[1] = f2b(o1 * scl);
}

// ---------------- V transpose (PERMUTED): Vt[bh][d][col] ----------------
// Within each 64-kv block, column j holds kv = (j&3)*16 + (j>>2), matching the
// P-tile column layout produced by attn_v2 (lane c, subtile s -> col c*4+s).
__global__ __launch_bounds__(256) void v_transpose(
    const unsigned short* __restrict__ qkv, unsigned short* __restrict__ Vt) {
  __shared__ unsigned short t[64][33];
  const int st = blockIdx.x;   // 32 tiles of 64 kv
  const int dt = blockIdx.y;   // 2 tiles of 32 d
  const int bh = blockIdx.z;   // 32
  const int b = bh >> 4, h = bh & 15;
  const int tx = threadIdx.x, ty = threadIdx.y;  // (32, 8)
#pragma unroll
  for (int j = 0; j < 8; ++j)
    t[ty + j * 8][tx] =
        qkv[((long)b * S_LEN + st * 64 + ty + j * 8) * 3072 + 2048 + h * 64 + dt * 32 + tx];
  __syncthreads();
#pragma unroll
  for (int j = 0; j < 4; ++j) {
    const int d_local = ty + j * 8;          // 0..31
#pragma unroll
    for (int jj = 0; jj < 2; ++jj) {
      const int col = jj * 32 + tx;          // 0..63
      const int kv = (col & 3) * 16 + (col >> 2);
      Vt[((long)bh * 64 + dt * 32 + d_local) * S_LEN + st * 64 + col] = t[kv][d_local];
    }
  }
}

// ---------------- flash attention v2 ----------------
// 1 wave per block; wave owns 16 q-rows x 2 paired jobs (p, 127-p) -> uniform
// ~33 KV64-tiles/wave. K,V prefetched to registers one tile ahead. P through
// swizzled wave-private LDS. Full tiles mask-free; only last tile masks.
__device__ __forceinline__ void load_k(const unsigned short* __restrict__ Kp,
                                       int kpos, int c, int g, short8 kf[4][2]) {
#pragma unroll
  for (int s = 0; s < 4; ++s)
#pragma unroll
    for (int hh = 0; hh < 2; ++hh)
      kf[s][hh] = *(const short8*)(Kp + (long)(kpos + s * 16 + c) * 64 + hh * 32 + g * 8);
}
__device__ __forceinline__ void load_v(const unsigned short* __restrict__ Vp,
                                       int kpos, int c, int g, short8 vf[4][2]) {
#pragma unroll
  for (int dt = 0; dt < 4; ++dt)
#pragma unroll
    for (int hh = 0; hh < 2; ++hh)
      vf[dt][hh] = *(const short8*)(Vp + (long)(dt * 16 + c) * S_LEN + kpos + hh * 32 + g * 8);
}

template <bool MASKED, bool PREFETCH>
__device__ __forceinline__ void attn_tile(
    int kpos0, int qbase, int c, int g,
    const short8& q0, const short8& q1,
    short8 kf[4][2], short8 vf[4][2],
    f32x4 O[4], float mrow[4], float lrow[4],
    unsigned char* PwB,
    const unsigned short* __restrict__ Kp, const unsigned short* __restrict__ Vp) {
  f32x4 s[4];
#pragma unroll
  for (int sub = 0; sub < 4; ++sub) {
    f32x4 z = {};
    z = mfma16(q0, kf[sub][0], z);
    s[sub] = mfma16(q1, kf[sub][1], z);
  }
  if (PREFETCH) load_k(Kp, kpos0 + 64, c, g, kf);  // K(t+1): latency hidden under softmax+PV
  float sc[4];
#pragma unroll
  for (int r = 0; r < 4; ++r) {
    float a0 = s[0][r], a1 = s[1][r], a2 = s[2][r], a3 = s[3][r];
    if (MASKED) {
      const int q = qbase + g * 4 + r;
      a0 = (kpos0 + c <= q) ? a0 : -1e30f;
      a1 = (kpos0 + 16 + c <= q) ? a1 : -1e30f;
      a2 = (kpos0 + 32 + c <= q) ? a2 : -1e30f;
      a3 = (kpos0 + 48 + c <= q) ? a3 : -1e30f;
    }
    float mt = fmaxf(fmaxf(a0, a1), fmaxf(a2, a3));
    mt = fmaxf(mt, __shfl_xor(mt, 1));
    mt = fmaxf(mt, __shfl_xor(mt, 2));
    mt = fmaxf(mt, __shfl_xor(mt, 4));
    mt = fmaxf(mt, __shfl_xor(mt, 8));
    const float mnew = fmaxf(mrow[r], mt);
    sc[r] = __expf(mrow[r] - mnew);
    mrow[r] = mnew;
    a0 = __expf(a0 - mnew);
    a1 = __expf(a1 - mnew);
    a2 = __expf(a2 - mnew);
    a3 = __expf(a3 - mnew);
    float rs = (a0 + a1) + (a2 + a3);
    rs += __shfl_xor(rs, 1);
    rs += __shfl_xor(rs, 2);
    rs += __shfl_xor(rs, 4);
    rs += __shfl_xor(rs, 8);
    lrow[r] = lrow[r] * sc[r] + rs;
    // P row q=g*4+r, cols c*4+{0,1,2,3} (permuted kv order, matches Vt)
    unsigned int lo, hi;
    asm("v_cvt_pk_bf16_f32 %0, %1, %2" : "=v"(lo) : "v"(a0), "v"(a1));
    asm("v_cvt_pk_bf16_f32 %0, %1, %2" : "=v"(hi) : "v"(a2), "v"(a3));
    const int qr = g * 4 + r;
    *(uint2*)(PwB + qr * 128 + ((c * 8) ^ ((qr & 7) << 4))) = make_uint2(lo, hi);
  }
#pragma unroll
  for (int dt = 0; dt < 4; ++dt) {
    f32x4 o = O[dt];
    o[0] *= sc[0]; o[1] *= sc[1]; o[2] *= sc[2]; o[3] *= sc[3];
    O[dt] = o;
  }
  __builtin_amdgcn_wave_barrier();
  const int rb = c * 128, swz = (c & 7) << 4;
  const short8 pa0 = *(const short8*)(PwB + rb + ((g * 16) ^ swz));
  const short8 pa1 = *(const short8*)(PwB + rb + ((64 + g * 16) ^ swz));
#pragma unroll
  for (int dt = 0; dt < 4; ++dt) {
    O[dt] = mfma16(pa0, vf[dt][0], O[dt]);
    O[dt] = mfma16(pa1, vf[dt][1], O[dt]);
  }
  __builtin_amdgcn_wave_barrier();
  if (PREFETCH) load_v(Vp, kpos0 + 64, c, g, vf);  // V(t+1): hidden under next QK+softmax
}

__global__ __launch_bounds__(64) void attn_v2(
    const unsigned short* __restrict__ Qb, const unsigned short* __restrict__ Kb,
    const unsigned short* __restrict__ Vt, unsigned short* __restrict__ yb) {
  __shared__ __align__(16) unsigned char PwB[2048];
  const int flat = (int)blockIdx.x + ((int)blockIdx.y << 6);  // 0..2047
  const int xcd = flat & 7;              // dispatch round-robins XCDs
  const int jj = flat >> 3;              // 0..255
  const int bh = xcd * 4 + (jj >> 6);    // cluster 4 heads per XCD (2MB K+V < 4MB L2)
  const int pA = jj & 63;                // pair id; jobs p=pA and p=127-pA
  const int lane = (int)threadIdx.x & 63;
  const int g = lane >> 4, c = lane & 15;
  const int b = bh >> 4, h = bh & 15;
  const unsigned short* Kp = Kb + (long)bh * (S_LEN * 64);
  const unsigned short* Vp = Vt + (long)bh * (64 * S_LEN);
  short8 kf[4][2], vf[4][2];

  for (int job = 0; job < 2; ++job) {
    const int p = job ? (127 - pA) : pA;
    const int qbase = p << 4;
    const unsigned short* Qp = Qb + ((long)bh * S_LEN + qbase) * 64;
    const short8 q0 = *(const short8*)(Qp + c * 64 + g * 8);
    const short8 q1 = *(const short8*)(Qp + c * 64 + 32 + g * 8);
    f32x4 O[4] = {};
    float mrow[4] = {-1e30f, -1e30f, -1e30f, -1e30f};
    float lrow[4] = {0.f, 0.f, 0.f, 0.f};
    const int nfull = qbase >> 6;

    load_k(Kp, 0, c, g, kf);
    load_v(Vp, 0, c, g, vf);
    for (int t = 0; t < nfull; ++t)
      attn_tile<false, true>(t * 64, qbase, c, g, q0, q1, kf, vf, O, mrow, lrow, PwB, Kp, Vp);
    attn_tile<true, false>(nfull * 64, qbase, c, g, q0, q1, kf, vf, O, mrow, lrow, PwB, Kp, Vp);

    float inv[4];
#pragma unroll
    for (int r = 0; r < 4; ++r) inv[r] = 1.0f / lrow[r];
#pragma unroll
    for (int dt = 0; dt < 4; ++dt)
#pragma unroll
      for (int r = 0; r < 4; ++r) {
        long row = (long)b * S_LEN + qbase + g * 4 + r;
        yb[row * DMODEL + h * 64 + dt * 16 + c] = f2b(O[dt][r] * inv[r]);
      }
  }
}

extern "C" void kernel_launch(void* const* d_in, const int* in_sizes, int n_in,
                              void* d_out, int out_size, void* d_ws, size_t ws_size,
                              hipStream_t stream) {
  const float* x = (const float*)d_in[0];       // [2,2048,1024]
  const float* Wa = (const float*)d_in[1];      // [1024,3072]
  const float* Wp = (const float*)d_in[2];      // [1024,1024]
  float* out = (float*)d_out;

  char* ws = (char*)d_ws;
  size_t off = 0;
  auto alloc = [&](size_t bytes) -> void* {
    off = (off + 255) & ~(size_t)255;
    void* p = ws + off;
    off += bytes;
    return p;
  };
  unsigned short* xb   = (unsigned short*)alloc((size_t)4096 * 1024 * 2);
  unsigned short* WaT  = (unsigned short*)alloc((size_t)3072 * 1024 * 2);
  unsigned short* WpT  = (unsigned short*)alloc((size_t)1024 * 1024 * 2);
  unsigned short* qkvb = (unsigned short*)alloc((size_t)4096 * 3072 * 2);
  float2* tab          = (float2*)alloc((size_t)2048 * 32 * sizeof(float2));
  unsigned short* Qb   = (unsigned short*)alloc((size_t)32 * 2048 * 64 * 2);
  unsigned short* Kb   = (unsigned short*)alloc((size_t)32 * 2048 * 64 * 2);
  unsigned short* Vt   = (unsigned short*)alloc((size_t)32 * 2048 * 64 * 2);
  unsigned short* yb   = xb;  // alias: xb dead after gemm1

  dim3 tB(32, 8);
  cast_f32_bf16<<<4096, 256, 0, stream>>>(x, xb, (long)4096 * 1024);
  transpose_cast<<<dim3(96, 32), tB, 0, stream>>>(Wa, WaT, 1024, 3072);
  transpose_cast<<<dim3(32, 32), tB, 0, stream>>>(Wp, WpT, 1024, 1024);
  make_tab<<<256, 256, 0, stream>>>(tab);
  gemm_bt<1><<<dim3(32, 24), 256, 0, stream>>>(xb, WaT, (void*)qkvb, 4096, 3072, 1024);
  rope_scatter<<<16384, 256, 0, stream>>>(qkvb, tab, Qb, Kb);
  v_transpose<<<dim3(32, 2, 32), tB, 0, stream>>>(qkvb, Vt);
  attn_v2<<<dim3(64, 32), 64, 0, stream>>>(Qb, Kb, Vt, yb);
  gemm_bt<0><<<dim3(32, 8), 256, 0, stream>>>(yb, WpT, (void*)out, 4096, 1024, 1024);
}